// Round 22
// baseline (233.143 us; speedup 1.0000x reference)
//
#include <hip/hip_runtime.h>
#include <hip/hip_fp16.h>
#include <math.h>

#define B_ 64
#define T_ 12
#define N_ 307
#define I_ 3
#define R_ 64
#define D_ 10
#define M_ (B_*N_)      // 19648
#define TM_ (T_*M_)     // 235776

typedef _Float16 f16x8 __attribute__((ext_vector_type(8)));
typedef _Float16 f16x4 __attribute__((ext_vector_type(4)));
typedef float f32x4 __attribute__((ext_vector_type(4)));

__device__ __forceinline__ float sigm(float x){ return 1.f/(1.f+__expf(-x)); }

// pack two f32 -> one dword of 2 f16 (RTZ)
__device__ __forceinline__ unsigned pkh(float a, float b){
  unsigned r;
  asm("v_cvt_pkrtz_f16_f32 %0, %1, %2" : "=v"(r) : "v"(a), "v"(b));
  return r;
}

// ---------------- stage A ----------------
__global__ __launch_bounds__(256) void k_stageA(
    const float* __restrict__ x,
    const float* __restrict__ xw1, const float* __restrict__ xb1,
    const float* __restrict__ xw2, const float* __restrict__ xb2,
    const float* __restrict__ xw3, const float* __restrict__ xb3,
    const float* __restrict__ fw1, const float* __restrict__ fb1,
    const float* __restrict__ fw2, const float* __restrict__ fb2,
    const float* __restrict__ fw3, const float* __restrict__ fb3,
    float* __restrict__ g1)
{
  int idx = blockIdx.x*256 + threadIdx.x;
  int t = idx / M_;
  int m = idx - t*M_;
  int b = m / N_;
  int n = m - b*N_;
  const float* xp = x + (((size_t)b*T_ + t)*N_ + n)*I_;
  float xv[3] = {xp[0], xp[1], xp[2]};
  float e[3][10];
  #pragma unroll
  for (int i=0;i<3;++i){
    float h1[16];
    #pragma unroll
    for (int u=0;u<16;++u) h1[u] = sigm(xv[i]*xw1[u] + xb1[u]);
    float h2[2];
    #pragma unroll
    for (int v=0;v<2;++v){
      float a = xb2[v];
      #pragma unroll
      for (int u=0;u<16;++u) a += h1[u]*xw2[v*16+u];
      h2[v] = sigm(a);
    }
    #pragma unroll
    for (int d=0;d<10;++d) e[i][d] = xb3[d] + h2[0]*xw3[d*2] + h2[1]*xw3[d*2+1];
  }
  float in1[3];
  #pragma unroll
  for (int j=0;j<3;++j){
    float acc = 0.f;
    #pragma unroll
    for (int i=0;i<3;++i){
      float s = 0.f;
      #pragma unroll
      for (int d=0;d<10;++d) s += e[j][d]*e[i][d];
      s = fmaxf(s, 0.f);
      acc += s*xv[i];
    }
    in1[j] = xv[j] + acc;
  }
  float h1[16];
  #pragma unroll
  for (int u=0;u<16;++u)
    h1[u] = sigm(fb1[u] + in1[0]*fw1[u*3] + in1[1]*fw1[u*3+1] + in1[2]*fw1[u*3+2]);
  float h2[2];
  #pragma unroll
  for (int v=0;v<2;++v){
    float a = fb2[v];
    #pragma unroll
    for (int u=0;u<16;++u) a += h1[u]*fw2[v*16+u];
    h2[v] = sigm(a);
  }
  float* gp = g1 + (size_t)idx*10;
  #pragma unroll
  for (int d=0;d<10;++d) gp[d] = fb3[d] + h2[0]*fw3[d*2] + h2[1]*fw3[d*2+1];
}

// ---------------- k_prep ----------------
__global__ __launch_bounds__(256) void k_prep(
    const float* __restrict__ wpool, const float* __restrict__ bpool,
    const float* __restrict__ dw,
    float* __restrict__ Wp2, float* __restrict__ bp2)
{
  int d = blockIdx.x; int tid = threadIdx.x;
  __shared__ float WpS[64*68];    // [c][r]
  __shared__ float dwBT[64*68];   // [r][u]
  __shared__ float bp_s[64];
  for (int idx = tid; idx < 4096; idx += 256) {
    int c = idx >> 6, r = idx & 63;
    WpS[c*68 + r] = wpool[(size_t)d*4096 + idx];
  }
  for (int idx = tid; idx < 4096; idx += 256) {
    int u = idx >> 6, r = idx & 63;
    dwBT[r*68 + u] = dw[u*128 + 64 + r];
  }
  if (tid < 64) bp_s[tid] = bpool[d*64 + tid];
  __syncthreads();
  int u = tid & 63, cg = tid >> 6;
  #pragma unroll
  for (int j = 0; j < 16; ++j) {
    int c = cg*16 + j;
    float acc = 0.f;
    #pragma unroll 8
    for (int r = 0; r < 64; ++r) acc += WpS[c*68 + r] * dwBT[r*68 + u];
    Wp2[(size_t)d*4096 + u*64 + c] = acc;
  }
  if (tid < 64) {
    float acc = 0.f;
    #pragma unroll 8
    for (int r = 0; r < 64; ++r) acc += bp_s[r] * dwBT[r*68 + tid];
    bp2[d*64 + tid] = acc;
  }
}

// ---------------- k_wnf ----------------
__global__ __launch_bounds__(256) void k_wnf(
    const float* __restrict__ emb2, const float* __restrict__ Wp2,
    const float* __restrict__ bp2, const float* __restrict__ db,
    float* __restrict__ Wf, float* __restrict__ bf)
{
  int n = blockIdx.x; int tid = threadIdx.x;
  __shared__ float e_s[10];
  if (tid < 10) e_s[tid] = emb2[n*10 + tid];
  __syncthreads();
  #pragma unroll
  for (int e=0;e<16;++e){
    int i = e*256 + tid;
    float a = 0.f;
    #pragma unroll
    for (int d=0;d<10;++d) a += e_s[d]*Wp2[(size_t)d*4096 + i];
    Wf[(size_t)n*4096 + i] = a;
  }
  if (tid < 64){
    float a = db[tid];
    #pragma unroll
    for (int d=0;d<10;++d) a += e_s[d]*bp2[d*64 + tid];
    bf[n*64 + tid] = a;
  }
}

// ---------------- k_wpackM ----------------
__global__ __launch_bounds__(256) void k_wpackM(
    const float* __restrict__ wih2, const float* __restrict__ whh2,
    const float* __restrict__ wih1, const float* __restrict__ whh1,
    unsigned* __restrict__ Wh2, unsigned* __restrict__ Wx2,
    unsigned* __restrict__ Wh1, unsigned* __restrict__ Wx1)
{
  int i = blockIdx.x*256 + threadIdx.x;
  if (i < 192*32) {
    int wr = i >> 5, p = i & 31;
    Wh2[i] = pkh(whh2[wr*64 + 2*p], whh2[wr*64 + 2*p + 1]);
    Wx2[i] = pkh(wih2[wr*64 + 2*p], wih2[wr*64 + 2*p + 1]);
    Wh1[i] = pkh(whh1[wr*64 + 2*p], whh1[wr*64 + 2*p + 1]);
  }
  int j = i - 192*32;
  if (j >= 0 && j < 192*16) {
    int wr = j >> 4, p = j & 15;
    Wx1[j] = (p < 5) ? pkh(wih1[wr*10 + 2*p], wih1[wr*10 + 2*p + 1]) : 0u;
  }
}

// ---------------- k_gruM: MFMA GRU scan, double-buffered Ah/Ax, 1 barrier/step ----------------
template<int DIN, bool WFIN>
__global__ __launch_bounds__(256, 3) void k_gruM(
    const float* __restrict__ xseq,
    const unsigned* __restrict__ Whf,
    const unsigned* __restrict__ Wxf,
    const float* __restrict__ bih, const float* __restrict__ bhh,
    float* __restrict__ o_out)
{
  constexpr int XPR = (DIN == 64) ? 32 : 16;
  constexpr int XKS = XPR / 16;
  constexpr int XST = XPR + 4;
  __shared__ __align__(16) unsigned Ah_s[2][16*36];
  __shared__ __align__(16) unsigned Ax_s[2][16*XST];
  const int tid = threadIdx.x;
  const int lane = tid & 63, w = tid >> 6;
  const int fr = lane & 15, fq = lane >> 4;
  const int row0 = blockIdx.x * 16;
  const int u = w*16 + fr;

  f16x8 bh_r[2], bh_z[2], bh_n[2];
  #pragma unroll
  for (int ks = 0; ks < 2; ++ks) {
    bh_r[ks] = *(const f16x8*)&Whf[(size_t)u*32        + ks*16 + fq*4];
    bh_z[ks] = *(const f16x8*)&Whf[(size_t)(64+u)*32   + ks*16 + fq*4];
    bh_n[ks] = *(const f16x8*)&Whf[(size_t)(128+u)*32  + ks*16 + fq*4];
  }
  f16x8 bx_r[XKS], bx_z[XKS], bx_n[XKS];
  #pragma unroll
  for (int ks = 0; ks < XKS; ++ks) {
    bx_r[ks] = *(const f16x8*)&Wxf[(size_t)u*XPR       + ks*16 + fq*4];
    bx_z[ks] = *(const f16x8*)&Wxf[(size_t)(64+u)*XPR  + ks*16 + fq*4];
    bx_n[ks] = *(const f16x8*)&Wxf[(size_t)(128+u)*XPR + ks*16 + fq*4];
  }

  const float brc = bih[u]     + bhh[u];
  const float bzc = bih[64+u]  + bhh[64+u];
  const float bxn = bih[128+u];
  const float bhn = bhh[128+u];

  for (int i = tid; i < 2*16*36;  i += 256) ((unsigned*)Ah_s)[i] = 0u;
  for (int i = tid; i < 2*16*XST; i += 256) ((unsigned*)Ax_s)[i] = 0u;
  __syncthreads();   // zero-init ordered before t=0 staging (R11 race fix)

  size_t obase[4];
  #pragma unroll
  for (int reg = 0; reg < 4; ++reg) {
    int g = row0 + fq*4 + reg;
    if (WFIN) { int bb = g / N_, nn = g - bb*N_; obase[reg] = (((size_t)bb*T_)*N_ + nn)*64 + u; }
    else      { obase[reg] = (size_t)g*64 + u; }
  }
  const size_t tstep = WFIN ? (size_t)N_*64 : (size_t)M_*64;
  float hreg[4] = {0.f, 0.f, 0.f, 0.f};

  for (int t = 0; t < T_; ++t) {
    const int cb = t & 1;
    if (DIN == 64) {
      #pragma unroll
      for (int it = 0; it < 2; ++it) {
        int idx = tid + it*256;
        int row = idx >> 5, p = idx & 31;
        const float2 v = *(const float2*)&xseq[((size_t)t*M_ + row0 + row)*64 + 2*p];
        Ax_s[cb][row*XST + p] = pkh(v.x, v.y);
      }
    } else {
      if (tid < 80) {
        int row = tid / 5, p = tid - (tid/5)*5;
        const float2 v = *(const float2*)&xseq[((size_t)t*M_ + row0 + row)*10 + 2*p];
        Ax_s[cb][row*XST + p] = pkh(v.x, v.y);
      }
    }
    __syncthreads();   // x[cb] staged; h writeback from t-1 (into Ah[cb]) visible

    f32x4 ar  = {0.f,0.f,0.f,0.f}, az  = {0.f,0.f,0.f,0.f};
    f32x4 anh = {0.f,0.f,0.f,0.f}, anx = {0.f,0.f,0.f,0.f};
    #pragma unroll
    for (int ks = 0; ks < 2; ++ks) {
      f16x8 ah = *(const f16x8*)&Ah_s[cb][fr*36 + ks*16 + fq*4];
      ar  = __builtin_amdgcn_mfma_f32_16x16x32_f16(ah, bh_r[ks], ar,  0,0,0);
      az  = __builtin_amdgcn_mfma_f32_16x16x32_f16(ah, bh_z[ks], az,  0,0,0);
      anh = __builtin_amdgcn_mfma_f32_16x16x32_f16(ah, bh_n[ks], anh, 0,0,0);
    }
    #pragma unroll
    for (int ks = 0; ks < XKS; ++ks) {
      f16x8 ax = *(const f16x8*)&Ax_s[cb][fr*XST + ks*16 + fq*4];
      ar  = __builtin_amdgcn_mfma_f32_16x16x32_f16(ax, bx_r[ks], ar,  0,0,0);
      az  = __builtin_amdgcn_mfma_f32_16x16x32_f16(ax, bx_z[ks], az,  0,0,0);
      anx = __builtin_amdgcn_mfma_f32_16x16x32_f16(ax, bx_n[ks], anx, 0,0,0);
    }

    float o_new[4];
    #pragma unroll
    for (int reg = 0; reg < 4; ++reg) {
      float rg = sigm(ar[reg] + brc);
      float zg = sigm(az[reg] + bzc);
      float ng = tanhf(anx[reg] + bxn + rg*(anh[reg] + bhn));
      o_new[reg] = (1.f - zg)*ng + zg*hreg[reg];
      hreg[reg] = o_new[reg];
    }
    #pragma unroll
    for (int reg = 0; reg < 4; ++reg)
      o_out[obase[reg] + (size_t)t*tstep] = o_new[reg];

    unsigned pk[4];
    #pragma unroll
    for (int reg = 0; reg < 4; ++reg) {
      float pr = __shfl_xor(o_new[reg], 1);
      pk[reg] = pkh(o_new[reg], pr);
    }
    if ((fr & 1) == 0) {
      #pragma unroll
      for (int reg = 0; reg < 4; ++reg)
        Ah_s[cb^1][(fq*4 + reg)*36 + w*8 + (fr >> 1)] = pk[reg];
    }
    // next step's top barrier orders this writeback before its reads
  }
}

// ---------------- stage C ----------------
__global__ __launch_bounds__(256) void k_stageC(
    const float* __restrict__ out1, const float* __restrict__ emb1,
    const float* __restrict__ w1, const float* __restrict__ b1,
    const float* __restrict__ w2, const float* __restrict__ b2,
    const float* __restrict__ w3, const float* __restrict__ b3,
    float* __restrict__ ndv)
{
  int idx = blockIdx.x*256 + threadIdx.x;
  int m = idx % M_;
  int n = m % N_;
  float rv[64];
  const float4* r4 = (const float4*)(out1 + (size_t)idx*64);
  #pragma unroll
  for (int q=0;q<16;++q){ float4 v=r4[q]; rv[q*4]=v.x; rv[q*4+1]=v.y; rv[q*4+2]=v.z; rv[q*4+3]=v.w; }
  float h1[16];
  for (int u=0;u<16;++u){
    float a = b1[u];
    const float* wr = w1 + u*64;
    #pragma unroll
    for (int c=0;c<64;++c) a += rv[c]*wr[c];
    h1[u] = sigm(a);
  }
  float h2[2];
  #pragma unroll
  for (int v=0;v<2;++v){
    float a = b2[v];
    #pragma unroll
    for (int u=0;u<16;++u) a += h1[u]*w2[v*16+u];
    h2[v] = sigm(a);
  }
  #pragma unroll
  for (int d=0;d<10;++d){
    float f = b3[d] + h2[0]*w3[d*2] + h2[1]*w3[d*2+1];
    ndv[(size_t)idx*10 + d] = tanhf(emb1[n*10+d]*f);
  }
}

// ---------------- stage D v6: compact Vp (K=16 MFMA1) -> 37.8 KB LDS, 4 blocks/CU ----------------
__global__ __launch_bounds__(256, 4) void k_stageDM(
    const float* __restrict__ ndv, const float* __restrict__ out1, float* __restrict__ xg)
{
  const int tb = blockIdx.x;
  const int tid = threadIdx.x;
  const int lane = tid & 63, wid = tid >> 6;
  const int fr = lane & 15, fq = lane >> 4;

  __shared__ __align__(16) unsigned Vp_s[320*8];     // f16 pairs of V, K=16 (pairs 5..7 zero)
  __shared__ __align__(16) unsigned P_s[64*36];      // wave-private rows (16/wave)
  __shared__ __align__(16) unsigned O_s[2][64*36];   // double-buffered O^T chunk

  // stage compact V (pairs 0..4 real, 5..7 zero)
  for (int i = tid; i < 320*8; i += 256) {
    int nn = i >> 3, p = i & 7;
    float a = 0.f, b = 0.f;
    if (nn < N_ && p < 5) {
      const float2 v = *(const float2*)&ndv[((size_t)tb*N_ + nn)*10 + 2*p];
      a = v.x; b = v.y;
    }
    Vp_s[i] = pkh(a, b);
  }

  const float* ob = out1 + (size_t)tb*N_*64;

  // stage O chunk 0 (mapping p=it&31: store lanes sweep all banks)
  for (int it = tid; it < 512; it += 256) {
    int p = it & 31, cg = it >> 5;
    int m0 = 2*p;
    float4 a = make_float4(0.f,0.f,0.f,0.f), b = a;
    if (m0     < N_) a = *(const float4*)&ob[(size_t)m0*64 + cg*4];
    if (m0 + 1 < N_) b = *(const float4*)&ob[(size_t)(m0+1)*64 + cg*4];
    int c0 = cg*4;
    O_s[0][(c0+0)*36 + p] = pkh(a.x, b.x);
    O_s[0][(c0+1)*36 + p] = pkh(a.y, b.y);
    O_s[0][(c0+2)*36 + p] = pkh(a.z, b.z);
    O_s[0][(c0+3)*36 + p] = pkh(a.w, b.w);
  }
  __syncthreads();

  f32x4 acc[5][4];
  #pragma unroll
  for (int a = 0; a < 5; ++a)
    #pragma unroll
    for (int c = 0; c < 4; ++c)
      acc[a][c] = (f32x4){0.f, 0.f, 0.f, 0.f};

  for (int k = 0; k < 5; ++k) {
    const int cur = k & 1;
    const int mc = k*64;
    // prefetch next O chunk (overlaps the MFMA work below)
    if (k < 4) {
      int mcn = mc + 64;
      for (int it = tid; it < 512; it += 256) {
        int p = it & 31, cg = it >> 5;
        int m0 = mcn + 2*p;
        float4 a = make_float4(0.f,0.f,0.f,0.f), b = a;
        if (m0     < N_) a = *(const float4*)&ob[(size_t)m0*64 + cg*4];
        if (m0 + 1 < N_) b = *(const float4*)&ob[(size_t)(m0+1)*64 + cg*4];
        int c0 = cg*4;
        O_s[cur^1][(c0+0)*36 + p] = pkh(a.x, b.x);
        O_s[cur^1][(c0+1)*36 + p] = pkh(a.y, b.y);
        O_s[cur^1][(c0+2)*36 + p] = pkh(a.z, b.z);
        O_s[cur^1][(c0+3)*36 + p] = pkh(a.w, b.w);
      }
    }
    // hoist per-chunk fragments (K=16: f16x4 at pair-offset fq*2)
    f16x4 va[4];
    #pragma unroll
    for (int mt = 0; mt < 4; ++mt)
      va[mt] = *(const f16x4*)&Vp_s[(mc + mt*16 + fr)*8 + fq*2];
    f16x8 bo[2][4];
    #pragma unroll
    for (int ks = 0; ks < 2; ++ks)
      #pragma unroll
      for (int ct = 0; ct < 4; ++ct)
        bo[ks][ct] = *(const f16x8*)&O_s[cur][(ct*16 + fr)*36 + ks*16 + fq*4];

    // per n-tile: MFMA1 (K=16 transposed S) -> wave-private P -> MFMA2 accumulate
    #pragma unroll
    for (int j = 0; j < 5; ++j) {
      int nt = wid + 4*j;
      f16x4 vb = *(const f16x4*)&Vp_s[(nt*16 + fr)*8 + fq*2];
      #pragma unroll
      for (int mt = 0; mt < 4; ++mt) {
        f32x4 s = (f32x4){0.f,0.f,0.f,0.f};
        s = __builtin_amdgcn_mfma_f32_16x16x16f16(va[mt], vb, s, 0, 0, 0);
        unsigned p0 = pkh(fmaxf(s[0],0.f), fmaxf(s[1],0.f));
        unsigned p1 = pkh(fmaxf(s[2],0.f), fmaxf(s[3],0.f));
        *(uint2*)&P_s[(wid*16 + fr)*36 + mt*8 + fq*2] = make_uint2(p0, p1);
      }
      #pragma unroll
      for (int ks = 0; ks < 2; ++ks) {
        f16x8 af = *(const f16x8*)&P_s[(wid*16 + fr)*36 + ks*16 + fq*4];
        #pragma unroll
        for (int ct = 0; ct < 4; ++ct)
          acc[j][ct] = __builtin_amdgcn_mfma_f32_16x16x32_f16(af, bo[ks][ct], acc[j][ct], 0, 0, 0);
      }
    }
    __syncthreads();   // O_s[cur] reads done; prefetch of [cur^1] complete
  }

  // epilogue: xg = out1 + acc
  #pragma unroll
  for (int j = 0; j < 5; ++j) {
    #pragma unroll
    for (int ct = 0; ct < 4; ++ct) {
      int col = ct*16 + fr;
      #pragma unroll
      for (int reg = 0; reg < 4; ++reg) {
        int n = (wid + 4*j)*16 + fq*4 + reg;
        if (n < N_) {
          size_t base = (size_t)tb*N_*64 + (size_t)n*64 + col;
          xg[base] = out1[base] + acc[j][ct][reg];
        }
      }
    }
  }
}

// ---------------- stage E (MFMA) ----------------
__global__ __launch_bounds__(256) void k_stageEM(
    const float* xg_in, const float* __restrict__ out1,
    const float* __restrict__ Wf, const float* __restrict__ dw,
    const float* __restrict__ bf,
    float* xg_out)
{
  int n = blockIdx.y;
  int tile = blockIdx.x;
  const int tid = threadIdx.x;
  const int lane = tid & 63, w = tid >> 6;
  const int fr = lane & 15, fq = lane >> 4;
  __shared__ __align__(16) unsigned As[64*68];
  __shared__ __align__(16) unsigned Bs[64*68];
  __shared__ float bf_s[64];

  for (int idx = tid; idx < 1024; idx += 256) {
    int row = idx >> 4, c4 = idx & 15;
    size_t g = ((size_t)(tile*64 + row)*N_ + n)*64 + c4*4;
    float4 o  = *(const float4*)&out1[g];
    float4 xv = *(const float4*)&xg_in[g];
    As[row*68 + c4*2]          = pkh(o.x, o.y);
    As[row*68 + c4*2 + 1]      = pkh(o.z, o.w);
    As[row*68 + 32 + c4*2]     = pkh(xv.x, xv.y);
    As[row*68 + 32 + c4*2 + 1] = pkh(xv.z, xv.w);
    int u = row;
    float4 da = *(const float4*)&dw[u*128 + c4*4];
    float4 wf = *(const float4*)&Wf[(size_t)n*4096 + u*64 + c4*4];
    Bs[u*68 + c4*2]          = pkh(da.x, da.y);
    Bs[u*68 + c4*2 + 1]      = pkh(da.z, da.w);
    Bs[u*68 + 32 + c4*2]     = pkh(wf.x, wf.y);
    Bs[u*68 + 32 + c4*2 + 1] = pkh(wf.z, wf.w);
  }
  if (tid < 64) bf_s[tid] = bf[n*64 + tid];
  __syncthreads();

  f32x4 acc[4];
  #pragma unroll
  for (int ct = 0; ct < 4; ++ct) acc[ct] = (f32x4){0.f,0.f,0.f,0.f};

  #pragma unroll
  for (int ks = 0; ks < 4; ++ks) {
    f16x8 af = *(const f16x8*)&As[(w*16 + fr)*68 + ks*16 + fq*4];
    #pragma unroll
    for (int ct = 0; ct < 4; ++ct) {
      f16x8 bfr = *(const f16x8*)&Bs[(ct*16 + fr)*68 + ks*16 + fq*4];
      acc[ct] = __builtin_amdgcn_mfma_f32_16x16x32_f16(af, bfr, acc[ct], 0, 0, 0);
    }
  }

  #pragma unroll
  for (int ct = 0; ct < 4; ++ct) {
    int u = ct*16 + fr;
    float bfv = bf_s[u];
    #pragma unroll
    for (int reg = 0; reg < 4; ++reg) {
      int row = w*16 + fq*4 + reg;
      xg_out[((size_t)(tile*64 + row)*N_ + n)*64 + u] = acc[ct][reg] + bfv;
    }
  }
}

extern "C" void kernel_launch(void* const* d_in, const int* in_sizes, int n_in,
                              void* d_out, int out_size, void* d_ws, size_t ws_size,
                              hipStream_t stream)
{
  (void)in_sizes; (void)n_in; (void)out_size;
  const float* x    = (const float*)d_in[0];
  const float* emb1 = (const float*)d_in[1];
  const float* emb2 = (const float*)d_in[2];
  const float* xw1  = (const float*)d_in[3];
  const float* xb1  = (const float*)d_in[4];
  const float* xw2  = (const float*)d_in[5];
  const float* xb2  = (const float*)d_in[6];
  const float* xw3  = (const float*)d_in[7];
  const float* xb3  = (const float*)d_in[8];
  const float* fw1  = (const float*)d_in[9];
  const float* fb1  = (const float*)d_in[10];
  const float* fw2  = (const float*)d_in[11];
  const float* fb2  = (const float*)d_in[12];
  const float* fw3  = (const float*)d_in[13];
  const float* fb3  = (const float*)d_in[14];
  const float* c2w1 = (const float*)d_in[15];
  const float* c2b1 = (const float*)d_in[16];
  const float* c2w2 = (const float*)d_in[17];
  const float* c2b2 = (const float*)d_in[18];
  const float* c2w3 = (const float*)d_in[19];
  const float* c2b3 = (const float*)d_in[20];
  const float* g1wih= (const float*)d_in[21];
  const float* g1whh= (const float*)d_in[22];
  const float* g1bih= (const float*)d_in[23];
  const float* g1bhh= (const float*)d_in[24];
  const float* g2wih= (const float*)d_in[25];
  const float* g2whh= (const float*)d_in[26];
  const float* g2bih= (const float*)d_in[27];
  const float* g2bhh= (const float*)d_in[28];
  const float* wpool= (const float*)d_in[29];
  const float* bpool= (const float*)d_in[30];
  const float* dww  = (const float*)d_in[31];
  const float* dwb  = (const float*)d_in[32];
  float* out = (float*)d_out;

  float* ws = (float*)d_ws;
  float* g1_in = ws;                          // TM*10
  float* out1  = g1_in + (size_t)TM_*10;      // TM*64
  float* ndv   = out1 + (size_t)TM_*64;       // TM*10
  float* xg    = ndv + (size_t)TM_*10;        // TM*64
  float* Wf    = xg + (size_t)TM_*64;         // N*4096
  float* bf    = Wf + (size_t)N_*4096;        // N*64
  float* Wp2   = bf + (size_t)N_*64;          // 10*4096
  float* bp2   = Wp2 + 10*4096;               // 10*64
  unsigned* Wh2f = (unsigned*)(bp2 + 10*64);  // 192*32
  unsigned* Wx2f = Wh2f + 192*32;             // 192*32
  unsigned* Wh1f = Wx2f + 192*32;             // 192*32
  unsigned* Wx1f = Wh1f + 192*32;             // 192*16
  size_t need = ((size_t)((char*)(Wx1f + 192*16) - (char*)ws));
  if (ws_size < need) return;

  k_stageA<<<TM_/256, 256, 0, stream>>>(x, xw1,xb1,xw2,xb2,xw3,xb3, fw1,fb1,fw2,fb2,fw3,fb3, g1_in);
  k_prep<<<10, 256, 0, stream>>>(wpool, bpool, dww, Wp2, bp2);
  k_wnf<<<N_, 256, 0, stream>>>(emb2, Wp2, bp2, dwb, Wf, bf);
  k_wpackM<<<(192*32 + 192*16 + 255)/256, 256, 0, stream>>>(
      g2wih, g2whh, g1wih, g1whh, Wh2f, Wx2f, Wh1f, Wx1f);

  // GRU1: x = g1_in (DIN=10), output out1 [T][M][64]
  k_gruM<10,false><<<M_/16, 256, 0, stream>>>(g1_in, Wh1f, Wx1f, g1bih, g1bhh, out1);

  k_stageC<<<TM_/256, 256, 0, stream>>>(out1, emb1, c2w1,c2b1,c2w2,c2b2,c2w3,c2b3, ndv);
  k_stageDM<<<T_*B_, 256, 0, stream>>>(ndv, out1, xg);
  k_stageEM<<<dim3(12, N_), 256, 0, stream>>>(xg, out1, Wf, dww, bf, xg);

  // GRU2: x = xg (DIN=64), output [B][T][N][64]
  k_gruM<64,true><<<M_/16, 256, 0, stream>>>(xg, Wh2f, Wx2f, g2bih, g2bhh, out);
}

// Round 23
// 224.776 us; speedup vs baseline: 1.0372x; 1.0372x over previous
//
#include <hip/hip_runtime.h>
#include <hip/hip_fp16.h>
#include <math.h>

#define B_ 64
#define T_ 12
#define N_ 307
#define I_ 3
#define R_ 64
#define D_ 10
#define M_ (B_*N_)      // 19648
#define TM_ (T_*M_)     // 235776

typedef _Float16 f16x8 __attribute__((ext_vector_type(8)));
typedef float f32x4 __attribute__((ext_vector_type(4)));

__device__ __forceinline__ float sigm(float x){ return 1.f/(1.f+__expf(-x)); }

// pack two f32 -> one dword of 2 f16 (RTZ)
__device__ __forceinline__ unsigned pkh(float a, float b){
  unsigned r;
  asm("v_cvt_pkrtz_f16_f32 %0, %1, %2" : "=v"(r) : "v"(a), "v"(b));
  return r;
}

// ---------------- stage A ----------------
__global__ __launch_bounds__(256) void k_stageA(
    const float* __restrict__ x,
    const float* __restrict__ xw1, const float* __restrict__ xb1,
    const float* __restrict__ xw2, const float* __restrict__ xb2,
    const float* __restrict__ xw3, const float* __restrict__ xb3,
    const float* __restrict__ fw1, const float* __restrict__ fb1,
    const float* __restrict__ fw2, const float* __restrict__ fb2,
    const float* __restrict__ fw3, const float* __restrict__ fb3,
    float* __restrict__ g1)
{
  int idx = blockIdx.x*256 + threadIdx.x;
  int t = idx / M_;
  int m = idx - t*M_;
  int b = m / N_;
  int n = m - b*N_;
  const float* xp = x + (((size_t)b*T_ + t)*N_ + n)*I_;
  float xv[3] = {xp[0], xp[1], xp[2]};
  float e[3][10];
  #pragma unroll
  for (int i=0;i<3;++i){
    float h1[16];
    #pragma unroll
    for (int u=0;u<16;++u) h1[u] = sigm(xv[i]*xw1[u] + xb1[u]);
    float h2[2];
    #pragma unroll
    for (int v=0;v<2;++v){
      float a = xb2[v];
      #pragma unroll
      for (int u=0;u<16;++u) a += h1[u]*xw2[v*16+u];
      h2[v] = sigm(a);
    }
    #pragma unroll
    for (int d=0;d<10;++d) e[i][d] = xb3[d] + h2[0]*xw3[d*2] + h2[1]*xw3[d*2+1];
  }
  float in1[3];
  #pragma unroll
  for (int j=0;j<3;++j){
    float acc = 0.f;
    #pragma unroll
    for (int i=0;i<3;++i){
      float s = 0.f;
      #pragma unroll
      for (int d=0;d<10;++d) s += e[j][d]*e[i][d];
      s = fmaxf(s, 0.f);
      acc += s*xv[i];
    }
    in1[j] = xv[j] + acc;
  }
  float h1[16];
  #pragma unroll
  for (int u=0;u<16;++u)
    h1[u] = sigm(fb1[u] + in1[0]*fw1[u*3] + in1[1]*fw1[u*3+1] + in1[2]*fw1[u*3+2]);
  float h2[2];
  #pragma unroll
  for (int v=0;v<2;++v){
    float a = fb2[v];
    #pragma unroll
    for (int u=0;u<16;++u) a += h1[u]*fw2[v*16+u];
    h2[v] = sigm(a);
  }
  float* gp = g1 + (size_t)idx*10;
  #pragma unroll
  for (int d=0;d<10;++d) gp[d] = fb3[d] + h2[0]*fw3[d*2] + h2[1]*fw3[d*2+1];
}

// ---------------- k_prep ----------------
__global__ __launch_bounds__(256) void k_prep(
    const float* __restrict__ wpool, const float* __restrict__ bpool,
    const float* __restrict__ dw,
    float* __restrict__ Wp2, float* __restrict__ bp2)
{
  int d = blockIdx.x; int tid = threadIdx.x;
  __shared__ float WpS[64*68];    // [c][r]
  __shared__ float dwBT[64*68];   // [r][u]
  __shared__ float bp_s[64];
  for (int idx = tid; idx < 4096; idx += 256) {
    int c = idx >> 6, r = idx & 63;
    WpS[c*68 + r] = wpool[(size_t)d*4096 + idx];
  }
  for (int idx = tid; idx < 4096; idx += 256) {
    int u = idx >> 6, r = idx & 63;
    dwBT[r*68 + u] = dw[u*128 + 64 + r];
  }
  if (tid < 64) bp_s[tid] = bpool[d*64 + tid];
  __syncthreads();
  int u = tid & 63, cg = tid >> 6;
  #pragma unroll
  for (int j = 0; j < 16; ++j) {
    int c = cg*16 + j;
    float acc = 0.f;
    #pragma unroll 8
    for (int r = 0; r < 64; ++r) acc += WpS[c*68 + r] * dwBT[r*68 + u];
    Wp2[(size_t)d*4096 + u*64 + c] = acc;
  }
  if (tid < 64) {
    float acc = 0.f;
    #pragma unroll 8
    for (int r = 0; r < 64; ++r) acc += bp_s[r] * dwBT[r*68 + tid];
    bp2[d*64 + tid] = acc;
  }
}

// ---------------- k_wnf ----------------
__global__ __launch_bounds__(256) void k_wnf(
    const float* __restrict__ emb2, const float* __restrict__ Wp2,
    const float* __restrict__ bp2, const float* __restrict__ db,
    float* __restrict__ Wf, float* __restrict__ bf)
{
  int n = blockIdx.x; int tid = threadIdx.x;
  __shared__ float e_s[10];
  if (tid < 10) e_s[tid] = emb2[n*10 + tid];
  __syncthreads();
  #pragma unroll
  for (int e=0;e<16;++e){
    int i = e*256 + tid;
    float a = 0.f;
    #pragma unroll
    for (int d=0;d<10;++d) a += e_s[d]*Wp2[(size_t)d*4096 + i];
    Wf[(size_t)n*4096 + i] = a;
  }
  if (tid < 64){
    float a = db[tid];
    #pragma unroll
    for (int d=0;d<10;++d) a += e_s[d]*bp2[d*64 + tid];
    bf[n*64 + tid] = a;
  }
}

// ---------------- k_wpackM ----------------
__global__ __launch_bounds__(256) void k_wpackM(
    const float* __restrict__ wih2, const float* __restrict__ whh2,
    const float* __restrict__ wih1, const float* __restrict__ whh1,
    unsigned* __restrict__ Wh2, unsigned* __restrict__ Wx2,
    unsigned* __restrict__ Wh1, unsigned* __restrict__ Wx1)
{
  int i = blockIdx.x*256 + threadIdx.x;
  if (i < 192*32) {
    int wr = i >> 5, p = i & 31;
    Wh2[i] = pkh(whh2[wr*64 + 2*p], whh2[wr*64 + 2*p + 1]);
    Wx2[i] = pkh(wih2[wr*64 + 2*p], wih2[wr*64 + 2*p + 1]);
    Wh1[i] = pkh(whh1[wr*64 + 2*p], whh1[wr*64 + 2*p + 1]);
  }
  int j = i - 192*32;
  if (j >= 0 && j < 192*16) {
    int wr = j >> 4, p = j & 15;
    Wx1[j] = (p < 5) ? pkh(wih1[wr*10 + 2*p], wih1[wr*10 + 2*p + 1]) : 0u;
  }
}

// ---------------- k_gruM: MFMA GRU scan, double-buffered Ah/Ax, 1 barrier/step ----------------
template<int DIN, bool WFIN>
__global__ __launch_bounds__(256, 3) void k_gruM(
    const float* __restrict__ xseq,
    const unsigned* __restrict__ Whf,
    const unsigned* __restrict__ Wxf,
    const float* __restrict__ bih, const float* __restrict__ bhh,
    float* __restrict__ o_out)
{
  constexpr int XPR = (DIN == 64) ? 32 : 16;
  constexpr int XKS = XPR / 16;
  constexpr int XST = XPR + 4;
  __shared__ __align__(16) unsigned Ah_s[2][16*36];
  __shared__ __align__(16) unsigned Ax_s[2][16*XST];
  const int tid = threadIdx.x;
  const int lane = tid & 63, w = tid >> 6;
  const int fr = lane & 15, fq = lane >> 4;
  const int row0 = blockIdx.x * 16;
  const int u = w*16 + fr;

  f16x8 bh_r[2], bh_z[2], bh_n[2];
  #pragma unroll
  for (int ks = 0; ks < 2; ++ks) {
    bh_r[ks] = *(const f16x8*)&Whf[(size_t)u*32        + ks*16 + fq*4];
    bh_z[ks] = *(const f16x8*)&Whf[(size_t)(64+u)*32   + ks*16 + fq*4];
    bh_n[ks] = *(const f16x8*)&Whf[(size_t)(128+u)*32  + ks*16 + fq*4];
  }
  f16x8 bx_r[XKS], bx_z[XKS], bx_n[XKS];
  #pragma unroll
  for (int ks = 0; ks < XKS; ++ks) {
    bx_r[ks] = *(const f16x8*)&Wxf[(size_t)u*XPR       + ks*16 + fq*4];
    bx_z[ks] = *(const f16x8*)&Wxf[(size_t)(64+u)*XPR  + ks*16 + fq*4];
    bx_n[ks] = *(const f16x8*)&Wxf[(size_t)(128+u)*XPR + ks*16 + fq*4];
  }

  const float brc = bih[u]     + bhh[u];
  const float bzc = bih[64+u]  + bhh[64+u];
  const float bxn = bih[128+u];
  const float bhn = bhh[128+u];

  for (int i = tid; i < 2*16*36;  i += 256) ((unsigned*)Ah_s)[i] = 0u;
  for (int i = tid; i < 2*16*XST; i += 256) ((unsigned*)Ax_s)[i] = 0u;
  __syncthreads();   // zero-init ordered before t=0 staging (R11 race fix)

  size_t obase[4];
  #pragma unroll
  for (int reg = 0; reg < 4; ++reg) {
    int g = row0 + fq*4 + reg;
    if (WFIN) { int bb = g / N_, nn = g - bb*N_; obase[reg] = (((size_t)bb*T_)*N_ + nn)*64 + u; }
    else      { obase[reg] = (size_t)g*64 + u; }
  }
  const size_t tstep = WFIN ? (size_t)N_*64 : (size_t)M_*64;
  float hreg[4] = {0.f, 0.f, 0.f, 0.f};

  for (int t = 0; t < T_; ++t) {
    const int cb = t & 1;
    if (DIN == 64) {
      #pragma unroll
      for (int it = 0; it < 2; ++it) {
        int idx = tid + it*256;
        int row = idx >> 5, p = idx & 31;
        const float2 v = *(const float2*)&xseq[((size_t)t*M_ + row0 + row)*64 + 2*p];
        Ax_s[cb][row*XST + p] = pkh(v.x, v.y);
      }
    } else {
      if (tid < 80) {
        int row = tid / 5, p = tid - (tid/5)*5;
        const float2 v = *(const float2*)&xseq[((size_t)t*M_ + row0 + row)*10 + 2*p];
        Ax_s[cb][row*XST + p] = pkh(v.x, v.y);
      }
    }
    __syncthreads();   // x[cb] staged; h writeback from t-1 (into Ah[cb]) visible

    f32x4 ar  = {0.f,0.f,0.f,0.f}, az  = {0.f,0.f,0.f,0.f};
    f32x4 anh = {0.f,0.f,0.f,0.f}, anx = {0.f,0.f,0.f,0.f};
    #pragma unroll
    for (int ks = 0; ks < 2; ++ks) {
      f16x8 ah = *(const f16x8*)&Ah_s[cb][fr*36 + ks*16 + fq*4];
      ar  = __builtin_amdgcn_mfma_f32_16x16x32_f16(ah, bh_r[ks], ar,  0,0,0);
      az  = __builtin_amdgcn_mfma_f32_16x16x32_f16(ah, bh_z[ks], az,  0,0,0);
      anh = __builtin_amdgcn_mfma_f32_16x16x32_f16(ah, bh_n[ks], anh, 0,0,0);
    }
    #pragma unroll
    for (int ks = 0; ks < XKS; ++ks) {
      f16x8 ax = *(const f16x8*)&Ax_s[cb][fr*XST + ks*16 + fq*4];
      ar  = __builtin_amdgcn_mfma_f32_16x16x32_f16(ax, bx_r[ks], ar,  0,0,0);
      az  = __builtin_amdgcn_mfma_f32_16x16x32_f16(ax, bx_z[ks], az,  0,0,0);
      anx = __builtin_amdgcn_mfma_f32_16x16x32_f16(ax, bx_n[ks], anx, 0,0,0);
    }

    float o_new[4];
    #pragma unroll
    for (int reg = 0; reg < 4; ++reg) {
      float rg = sigm(ar[reg] + brc);
      float zg = sigm(az[reg] + bzc);
      float ng = tanhf(anx[reg] + bxn + rg*(anh[reg] + bhn));
      o_new[reg] = (1.f - zg)*ng + zg*hreg[reg];
      hreg[reg] = o_new[reg];
    }
    #pragma unroll
    for (int reg = 0; reg < 4; ++reg)
      o_out[obase[reg] + (size_t)t*tstep] = o_new[reg];

    unsigned pk[4];
    #pragma unroll
    for (int reg = 0; reg < 4; ++reg) {
      float pr = __shfl_xor(o_new[reg], 1);
      pk[reg] = pkh(o_new[reg], pr);
    }
    if ((fr & 1) == 0) {
      #pragma unroll
      for (int reg = 0; reg < 4; ++reg)
        Ah_s[cb^1][(fq*4 + reg)*36 + w*8 + (fr >> 1)] = pk[reg];
    }
    // next step's top barrier orders this writeback before its reads
  }
}

// ---------------- stage C ----------------
__global__ __launch_bounds__(256) void k_stageC(
    const float* __restrict__ out1, const float* __restrict__ emb1,
    const float* __restrict__ w1, const float* __restrict__ b1,
    const float* __restrict__ w2, const float* __restrict__ b2,
    const float* __restrict__ w3, const float* __restrict__ b3,
    float* __restrict__ ndv)
{
  int idx = blockIdx.x*256 + threadIdx.x;
  int m = idx % M_;
  int n = m % N_;
  float rv[64];
  const float4* r4 = (const float4*)(out1 + (size_t)idx*64);
  #pragma unroll
  for (int q=0;q<16;++q){ float4 v=r4[q]; rv[q*4]=v.x; rv[q*4+1]=v.y; rv[q*4+2]=v.z; rv[q*4+3]=v.w; }
  float h1[16];
  for (int u=0;u<16;++u){
    float a = b1[u];
    const float* wr = w1 + u*64;
    #pragma unroll
    for (int c=0;c<64;++c) a += rv[c]*wr[c];
    h1[u] = sigm(a);
  }
  float h2[2];
  #pragma unroll
  for (int v=0;v<2;++v){
    float a = b2[v];
    #pragma unroll
    for (int u=0;u<16;++u) a += h1[u]*w2[v*16+u];
    h2[v] = sigm(a);
  }
  #pragma unroll
  for (int d=0;d<10;++d){
    float f = b3[d] + h2[0]*w3[d*2] + h2[1]*w3[d*2+1];
    ndv[(size_t)idx*10 + d] = tanhf(emb1[n*10+d]*f);
  }
}

// ---------------- stage D v4 (R21 form, best verified) ----------------
__global__ __launch_bounds__(256, 3) void k_stageDM(
    const float* __restrict__ ndv, const float* __restrict__ out1, float* __restrict__ xg)
{
  const int tb = blockIdx.x;
  const int tid = threadIdx.x;
  const int lane = tid & 63, wid = tid >> 6;
  const int fr = lane & 15, fq = lane >> 4;

  __shared__ __align__(16) unsigned Vp_s[320*20];
  __shared__ __align__(16) unsigned P_s[64*36];
  __shared__ __align__(16) unsigned O_s[2][64*36];

  for (int i = tid; i < 320*20; i += 256) {
    int nn = i / 20, p = i - (i/20)*20;
    float a = 0.f, b = 0.f;
    if (nn < N_ && p < 5) {
      const float2 v = *(const float2*)&ndv[((size_t)tb*N_ + nn)*10 + 2*p];
      a = v.x; b = v.y;
    }
    Vp_s[i] = pkh(a, b);
  }

  const float* ob = out1 + (size_t)tb*N_*64;

  for (int it = tid; it < 512; it += 256) {
    int p = it & 31, cg = it >> 5;
    int m0 = 2*p;
    float4 a = make_float4(0.f,0.f,0.f,0.f), b = a;
    if (m0     < N_) a = *(const float4*)&ob[(size_t)m0*64 + cg*4];
    if (m0 + 1 < N_) b = *(const float4*)&ob[(size_t)(m0+1)*64 + cg*4];
    int c0 = cg*4;
    O_s[0][(c0+0)*36 + p] = pkh(a.x, b.x);
    O_s[0][(c0+1)*36 + p] = pkh(a.y, b.y);
    O_s[0][(c0+2)*36 + p] = pkh(a.z, b.z);
    O_s[0][(c0+3)*36 + p] = pkh(a.w, b.w);
  }
  __syncthreads();

  f32x4 acc[5][4];
  #pragma unroll
  for (int a = 0; a < 5; ++a)
    #pragma unroll
    for (int c = 0; c < 4; ++c)
      acc[a][c] = (f32x4){0.f, 0.f, 0.f, 0.f};

  for (int k = 0; k < 5; ++k) {
    const int cur = k & 1;
    const int mc = k*64;
    if (k < 4) {
      int mcn = mc + 64;
      for (int it = tid; it < 512; it += 256) {
        int p = it & 31, cg = it >> 5;
        int m0 = mcn + 2*p;
        float4 a = make_float4(0.f,0.f,0.f,0.f), b = a;
        if (m0     < N_) a = *(const float4*)&ob[(size_t)m0*64 + cg*4];
        if (m0 + 1 < N_) b = *(const float4*)&ob[(size_t)(m0+1)*64 + cg*4];
        int c0 = cg*4;
        O_s[cur^1][(c0+0)*36 + p] = pkh(a.x, b.x);
        O_s[cur^1][(c0+1)*36 + p] = pkh(a.y, b.y);
        O_s[cur^1][(c0+2)*36 + p] = pkh(a.z, b.z);
        O_s[cur^1][(c0+3)*36 + p] = pkh(a.w, b.w);
      }
    }
    f16x8 va[4];
    #pragma unroll
    for (int mt = 0; mt < 4; ++mt)
      va[mt] = *(const f16x8*)&Vp_s[(mc + mt*16 + fr)*20 + fq*4];
    f16x8 bo[2][4];
    #pragma unroll
    for (int ks = 0; ks < 2; ++ks)
      #pragma unroll
      for (int ct = 0; ct < 4; ++ct)
        bo[ks][ct] = *(const f16x8*)&O_s[cur][(ct*16 + fr)*36 + ks*16 + fq*4];

    #pragma unroll
    for (int j = 0; j < 5; ++j) {
      int nt = wid + 4*j;
      f16x8 vb = *(const f16x8*)&Vp_s[(nt*16 + fr)*20 + fq*4];
      #pragma unroll
      for (int mt = 0; mt < 4; ++mt) {
        f32x4 s = (f32x4){0.f,0.f,0.f,0.f};
        s = __builtin_amdgcn_mfma_f32_16x16x32_f16(va[mt], vb, s, 0, 0, 0);
        unsigned p0 = pkh(fmaxf(s[0],0.f), fmaxf(s[1],0.f));
        unsigned p1 = pkh(fmaxf(s[2],0.f), fmaxf(s[3],0.f));
        *(uint2*)&P_s[(wid*16 + fr)*36 + mt*8 + fq*2] = make_uint2(p0, p1);
      }
      #pragma unroll
      for (int ks = 0; ks < 2; ++ks) {
        f16x8 af = *(const f16x8*)&P_s[(wid*16 + fr)*36 + ks*16 + fq*4];
        #pragma unroll
        for (int ct = 0; ct < 4; ++ct)
          acc[j][ct] = __builtin_amdgcn_mfma_f32_16x16x32_f16(af, bo[ks][ct], acc[j][ct], 0, 0, 0);
      }
    }
    __syncthreads();
  }

  #pragma unroll
  for (int j = 0; j < 5; ++j) {
    #pragma unroll
    for (int ct = 0; ct < 4; ++ct) {
      int col = ct*16 + fr;
      #pragma unroll
      for (int reg = 0; reg < 4; ++reg) {
        int n = (wid + 4*j)*16 + fq*4 + reg;
        if (n < N_) {
          size_t base = (size_t)tb*N_*64 + (size_t)n*64 + col;
          xg[base] = out1[base] + acc[j][ct][reg];
        }
      }
    }
  }
}

// ---------------- stage E (MFMA) ----------------
__global__ __launch_bounds__(256) void k_stageEM(
    const float* xg_in, const float* __restrict__ out1,
    const float* __restrict__ Wf, const float* __restrict__ dw,
    const float* __restrict__ bf,
    float* xg_out)
{
  int n = blockIdx.y;
  int tile = blockIdx.x;
  const int tid = threadIdx.x;
  const int lane = tid & 63, w = tid >> 6;
  const int fr = lane & 15, fq = lane >> 4;
  __shared__ __align__(16) unsigned As[64*68];
  __shared__ __align__(16) unsigned Bs[64*68];
  __shared__ float bf_s[64];

  for (int idx = tid; idx < 1024; idx += 256) {
    int row = idx >> 4, c4 = idx & 15;
    size_t g = ((size_t)(tile*64 + row)*N_ + n)*64 + c4*4;
    float4 o  = *(const float4*)&out1[g];
    float4 xv = *(const float4*)&xg_in[g];
    As[row*68 + c4*2]          = pkh(o.x, o.y);
    As[row*68 + c4*2 + 1]      = pkh(o.z, o.w);
    As[row*68 + 32 + c4*2]     = pkh(xv.x, xv.y);
    As[row*68 + 32 + c4*2 + 1] = pkh(xv.z, xv.w);
    int u = row;
    float4 da = *(const float4*)&dw[u*128 + c4*4];
    float4 wf = *(const float4*)&Wf[(size_t)n*4096 + u*64 + c4*4];
    Bs[u*68 + c4*2]          = pkh(da.x, da.y);
    Bs[u*68 + c4*2 + 1]      = pkh(da.z, da.w);
    Bs[u*68 + 32 + c4*2]     = pkh(wf.x, wf.y);
    Bs[u*68 + 32 + c4*2 + 1] = pkh(wf.z, wf.w);
  }
  if (tid < 64) bf_s[tid] = bf[n*64 + tid];
  __syncthreads();

  f32x4 acc[4];
  #pragma unroll
  for (int ct = 0; ct < 4; ++ct) acc[ct] = (f32x4){0.f,0.f,0.f,0.f};

  #pragma unroll
  for (int ks = 0; ks < 4; ++ks) {
    f16x8 af = *(const f16x8*)&As[(w*16 + fr)*68 + ks*16 + fq*4];
    #pragma unroll
    for (int ct = 0; ct < 4; ++ct) {
      f16x8 bfr = *(const f16x8*)&Bs[(ct*16 + fr)*68 + ks*16 + fq*4];
      acc[ct] = __builtin_amdgcn_mfma_f32_16x16x32_f16(af, bfr, acc[ct], 0, 0, 0);
    }
  }

  #pragma unroll
  for (int ct = 0; ct < 4; ++ct) {
    int u = ct*16 + fr;
    float bfv = bf_s[u];
    #pragma unroll
    for (int reg = 0; reg < 4; ++reg) {
      int row = w*16 + fq*4 + reg;
      xg_out[((size_t)(tile*64 + row)*N_ + n)*64 + u] = acc[ct][reg] + bfv;
    }
  }
}

extern "C" void kernel_launch(void* const* d_in, const int* in_sizes, int n_in,
                              void* d_out, int out_size, void* d_ws, size_t ws_size,
                              hipStream_t stream)
{
  (void)in_sizes; (void)n_in; (void)out_size;
  const float* x    = (const float*)d_in[0];
  const float* emb1 = (const float*)d_in[1];
  const float* emb2 = (const float*)d_in[2];
  const float* xw1  = (const float*)d_in[3];
  const float* xb1  = (const float*)d_in[4];
  const float* xw2  = (const float*)d_in[5];
  const float* xb2  = (const float*)d_in[6];
  const float* xw3  = (const float*)d_in[7];
  const float* xb3  = (const float*)d_in[8];
  const float* fw1  = (const float*)d_in[9];
  const float* fb1  = (const float*)d_in[10];
  const float* fw2  = (const float*)d_in[11];
  const float* fb2  = (const float*)d_in[12];
  const float* fw3  = (const float*)d_in[13];
  const float* fb3  = (const float*)d_in[14];
  const float* c2w1 = (const float*)d_in[15];
  const float* c2b1 = (const float*)d_in[16];
  const float* c2w2 = (const float*)d_in[17];
  const float* c2b2 = (const float*)d_in[18];
  const float* c2w3 = (const float*)d_in[19];
  const float* c2b3 = (const float*)d_in[20];
  const float* g1wih= (const float*)d_in[21];
  const float* g1whh= (const float*)d_in[22];
  const float* g1bih= (const float*)d_in[23];
  const float* g1bhh= (const float*)d_in[24];
  const float* g2wih= (const float*)d_in[25];
  const float* g2whh= (const float*)d_in[26];
  const float* g2bih= (const float*)d_in[27];
  const float* g2bhh= (const float*)d_in[28];
  const float* wpool= (const float*)d_in[29];
  const float* bpool= (const float*)d_in[30];
  const float* dww  = (const float*)d_in[31];
  const float* dwb  = (const float*)d_in[32];
  float* out = (float*)d_out;

  float* ws = (float*)d_ws;
  float* g1_in = ws;                          // TM*10
  float* out1  = g1_in + (size_t)TM_*10;      // TM*64
  float* ndv   = out1 + (size_t)TM_*64;       // TM*10
  float* xg    = ndv + (size_t)TM_*10;        // TM*64
  float* Wf    = xg + (size_t)TM_*64;         // N*4096
  float* bf    = Wf + (size_t)N_*4096;        // N*64
  float* Wp2   = bf + (size_t)N_*64;          // 10*4096
  float* bp2   = Wp2 + 10*4096;               // 10*64
  unsigned* Wh2f = (unsigned*)(bp2 + 10*64);  // 192*32
  unsigned* Wx2f = Wh2f + 192*32;             // 192*32
  unsigned* Wh1f = Wx2f + 192*32;             // 192*32
  unsigned* Wx1f = Wh1f + 192*32;             // 192*16
  size_t need = ((size_t)((char*)(Wx1f + 192*16) - (char*)ws));
  if (ws_size < need) return;

  k_stageA<<<TM_/256, 256, 0, stream>>>(x, xw1,xb1,xw2,xb2,xw3,xb3, fw1,fb1,fw2,fb2,fw3,fb3, g1_in);
  k_prep<<<10, 256, 0, stream>>>(wpool, bpool, dww, Wp2, bp2);
  k_wnf<<<N_, 256, 0, stream>>>(emb2, Wp2, bp2, dwb, Wf, bf);
  k_wpackM<<<(192*32 + 192*16 + 255)/256, 256, 0, stream>>>(
      g2wih, g2whh, g1wih, g1whh, Wh2f, Wx2f, Wh1f, Wx1f);

  // GRU1: x = g1_in (DIN=10), output out1 [T][M][64]
  k_gruM<10,false><<<M_/16, 256, 0, stream>>>(g1_in, Wh1f, Wx1f, g1bih, g1bhh, out1);

  k_stageC<<<TM_/256, 256, 0, stream>>>(out1, emb1, c2w1,c2b1,c2w2,c2b2,c2w3,c2b3, ndv);
  k_stageDM<<<T_*B_, 256, 0, stream>>>(ndv, out1, xg);
  k_stageEM<<<dim3(12, N_), 256, 0, stream>>>(xg, out1, Wf, dww, bf, xg);

  // GRU2: x = xg (DIN=64), output [B][T][N][64]
  k_gruM<64,true><<<M_/16, 256, 0, stream>>>(xg, Wh2f, Wx2f, g2bih, g2bhh, out);
}